// Round 1
// baseline (1845.261 us; speedup 1.0000x reference)
//
#include <hip/hip_runtime.h>
#include <cstdint>
#include <cstddef>

#define EPS_ 1e-5f
// sizes
#define NATOM 16384      // B*N
#define NB    8
#define NN    2048
#define NM    16
#define NHA   64
#define NHB   32
#define NHG   32
#define NVOCAB 100
#define NHINIT 92
#define NAMINO_ 2048

// ws layout (float offsets)
#define OFF_EMB      0                 // 16384*64   = 1048576
#define OFF_SELF     1048576           // 16384*128  = 2097152
#define OFF_NBR      3145728           // 16384*128  = 2097152
#define OFF_S        5242880           // 16384*64   = 1048576
#define OFF_T        6291456           // 100*64     = 6400
#define OFF_PART1    6297856           // 512*256    = 131072
#define OFF_PART2    6428928           // 512*128    = 65536
#define OFF_AFF1A    6494464           // 128
#define OFF_AFF1B    6494592           // 128
#define OFF_AFF2A    6494720           // 64
#define OFF_AFF2B    6494784           // 64
#define OFF_AMINO    6494848           // 2048*64    = 131072
#define OFF_PSUM     6625920           // 8*64
#define OFF_MSUM     6626432           // 8
#define OFF_MINIDX   6626440           // 1 (int)
#define WS_FLOATS    6626441

// ---------------- embed ----------------
__global__ void k_table(const float* __restrict__ et, const float* __restrict__ W,
                        const float* __restrict__ b, float* __restrict__ T)
{
    int v = blockIdx.x, c = threadIdx.x;
    float acc = b[c];
    for (int h = 0; h < NHINIT; ++h)
        acc = fmaf(et[v * NHINIT + h], W[h * NHA + c], acc);
    T[v * NHA + c] = acc;
}

__global__ void k_embed(const int* __restrict__ idx, const float* __restrict__ T,
                        float* __restrict__ emb)
{
    int t = blockIdx.x * 256 + threadIdx.x;
    emb[t] = T[idx[t >> 6] * NHA + (t & 63)];
}

// ---------------- per-atom projections ----------------
// selfp[bn][oc] = (emb[bn]*mask[bn]) @ W[0:64]   + fc_b[oc]
// nbrp [bn][oc] = (emb[bn]*mask[bn]) @ W[64:128]
__launch_bounds__(256)
__global__ void k_proj(const float* __restrict__ emb, const float* __restrict__ mask,
                       const float* __restrict__ fcW, const float* __restrict__ fcb,
                       float* __restrict__ selfp, float* __restrict__ nbrp)
{
    __shared__ float le[512];
    int t = threadIdx.x;
    {
        int j0 = t, j1 = t + 256;
        le[j0] = emb[blockIdx.x * 512 + j0] * mask[blockIdx.x * 8 + (j0 >> 6)];
        le[j1] = emb[blockIdx.x * 512 + j1] * mask[blockIdx.x * 8 + (j1 >> 6)];
    }
    __syncthreads();
    int half = t >> 7;        // 0 = self (with bias), 1 = nbr
    int oc = t & 127;
    float acc[8];
    float bias = half ? 0.f : fcb[oc];
#pragma unroll
    for (int a = 0; a < 8; ++a) acc[a] = bias;
    const float* Wbase = fcW + (half * 64) * 128 + oc;
    for (int c = 0; c < 64; ++c) {
        float w = Wbase[c * 128];
#pragma unroll
        for (int a = 0; a < 8; ++a) acc[a] = fmaf(le[a * 64 + c], w, acc[a]);
    }
    float* dst = half ? nbrp : selfp;
#pragma unroll
    for (int a = 0; a < 8; ++a) dst[(size_t)(blockIdx.x * 8 + a) * 128 + oc] = acc[a];
}

// ---------------- conv pass 1: z stats ----------------
// one wave per group of 8 atoms; lane owns channels (lane, lane+64)
__launch_bounds__(256, 2)
__global__ void k_conv_stats(const float* __restrict__ selfp, const float* __restrict__ nbrp,
                             const float* __restrict__ nbr_emb, const int* __restrict__ adj,
                             const float* __restrict__ mask, const float* __restrict__ fcW,
                             float* __restrict__ part1)
{
    __shared__ float se[4][512];
    __shared__ float red[4][256];
    const int lane = threadIdx.x & 63;
    const int wid = threadIdx.x >> 6;
    float we0[32], we1[32];
#pragma unroll
    for (int h = 0; h < 32; ++h) {
        we0[h] = fcW[(128 + h) * 128 + lane];
        we1[h] = fcW[(128 + h) * 128 + 64 + lane];
    }
    float sum0 = 0.f, sq0 = 0.f, sum1 = 0.f, sq1 = 0.f;
    const int base = (blockIdx.x * 4 + wid) * 8;
    for (int aa = 0; aa < 8; ++aa) {
        const int bn = base + aa;
        const int b = bn >> 11;
        const float mn = mask[bn];
        const float* src = nbr_emb + (size_t)bn * 512;
        __syncthreads();
#pragma unroll
        for (int k = 0; k < 8; ++k) se[wid][k * 64 + lane] = src[k * 64 + lane];
        int adjv = 0;
        if (lane < 16) adjv = adj[bn * 16 + lane];
        const float sp0 = selfp[(size_t)bn * 128 + lane];
        const float sp1 = selfp[(size_t)bn * 128 + 64 + lane];
        __syncthreads();
#pragma unroll 4
        for (int m = 0; m < 16; ++m) {
            const int a = __shfl(adjv, m);
            const float* np_ = nbrp + ((size_t)(b * NN + a)) * 128;
            float z0 = fmaf(mn, np_[lane], sp0);
            float z1 = fmaf(mn, np_[64 + lane], sp1);
#pragma unroll
            for (int h4 = 0; h4 < 8; ++h4) {
                const float4 e = *reinterpret_cast<const float4*>(&se[wid][m * 32 + h4 * 4]);
                z0 = fmaf(e.x, we0[h4 * 4 + 0], z0); z1 = fmaf(e.x, we1[h4 * 4 + 0], z1);
                z0 = fmaf(e.y, we0[h4 * 4 + 1], z0); z1 = fmaf(e.y, we1[h4 * 4 + 1], z1);
                z0 = fmaf(e.z, we0[h4 * 4 + 2], z0); z1 = fmaf(e.z, we1[h4 * 4 + 2], z1);
                z0 = fmaf(e.w, we0[h4 * 4 + 3], z0); z1 = fmaf(e.w, we1[h4 * 4 + 3], z1);
            }
            sum0 += z0; sq0 = fmaf(z0, z0, sq0);
            sum1 += z1; sq1 = fmaf(z1, z1, sq1);
        }
    }
    __syncthreads();
    red[wid][lane] = sum0; red[wid][64 + lane] = sum1;
    red[wid][128 + lane] = sq0; red[wid][192 + lane] = sq1;
    __syncthreads();
    const int t = threadIdx.x;
    float v = red[0][t] + red[1][t] + red[2][t] + red[3][t];
    part1[(size_t)blockIdx.x * 256 + t] = v;
}

__global__ void k_fin1(const float* __restrict__ part1, const float* __restrict__ g,
                       const float* __restrict__ b, float* __restrict__ A,
                       float* __restrict__ Bo, int nblocks)
{
    int c = threadIdx.x;  // 128
    float S = 0.f, Q = 0.f;
    for (int k = 0; k < nblocks; ++k) { S += part1[k * 256 + c]; Q += part1[k * 256 + 128 + c]; }
    float mean = S * (1.f / 262144.f);
    float var = Q * (1.f / 262144.f) - mean * mean;
    float a = g[c] * rsqrtf(var + EPS_);
    A[c] = a; Bo[c] = b[c] - mean * a;
}

// ---------------- conv pass 2: gate + s stats ----------------
__launch_bounds__(256, 2)
__global__ void k_conv_gate(const float* __restrict__ selfp, const float* __restrict__ nbrp,
                            const float* __restrict__ nbr_emb, const int* __restrict__ adj,
                            const float* __restrict__ mask, const float* __restrict__ fcW,
                            const float* __restrict__ aff1A, const float* __restrict__ aff1B,
                            float* __restrict__ s_out, float* __restrict__ part2)
{
    __shared__ float se[4][512];
    __shared__ float red[4][128];
    const int lane = threadIdx.x & 63;
    const int wid = threadIdx.x >> 6;
    float we0[32], we1[32];
#pragma unroll
    for (int h = 0; h < 32; ++h) {
        we0[h] = fcW[(128 + h) * 128 + lane];
        we1[h] = fcW[(128 + h) * 128 + 64 + lane];
    }
    const float a0 = aff1A[lane], b0 = aff1B[lane];
    const float a1 = aff1A[64 + lane], b1 = aff1B[64 + lane];
    float ssum = 0.f, ssq = 0.f;
    const int base = (blockIdx.x * 4 + wid) * 8;
    for (int aa = 0; aa < 8; ++aa) {
        const int bn = base + aa;
        const int b = bn >> 11;
        const float mn = mask[bn];
        const float* src = nbr_emb + (size_t)bn * 512;
        __syncthreads();
#pragma unroll
        for (int k = 0; k < 8; ++k) se[wid][k * 64 + lane] = src[k * 64 + lane];
        int adjv = 0;
        if (lane < 16) adjv = adj[bn * 16 + lane];
        const float sp0 = selfp[(size_t)bn * 128 + lane];
        const float sp1 = selfp[(size_t)bn * 128 + 64 + lane];
        __syncthreads();
        float sacc = 0.f;
#pragma unroll 4
        for (int m = 0; m < 16; ++m) {
            const int a = __shfl(adjv, m);
            const float* np_ = nbrp + ((size_t)(b * NN + a)) * 128;
            float z0 = fmaf(mn, np_[lane], sp0);
            float z1 = fmaf(mn, np_[64 + lane], sp1);
#pragma unroll
            for (int h4 = 0; h4 < 8; ++h4) {
                const float4 e = *reinterpret_cast<const float4*>(&se[wid][m * 32 + h4 * 4]);
                z0 = fmaf(e.x, we0[h4 * 4 + 0], z0); z1 = fmaf(e.x, we1[h4 * 4 + 0], z1);
                z0 = fmaf(e.y, we0[h4 * 4 + 1], z0); z1 = fmaf(e.y, we1[h4 * 4 + 1], z1);
                z0 = fmaf(e.z, we0[h4 * 4 + 2], z0); z1 = fmaf(e.z, we1[h4 * 4 + 2], z1);
                z0 = fmaf(e.w, we0[h4 * 4 + 3], z0); z1 = fmaf(e.w, we1[h4 * 4 + 3], z1);
            }
            float zh0 = fmaf(z0, a0, b0);          // filt channel lane
            float zh1 = fmaf(z1, a1, b1);          // core channel lane+64
            float f = 1.f / (1.f + __expf(-zh0));
            float r = fmaxf(zh1, 0.f);
            sacc = fmaf(f, r, sacc);
        }
        s_out[(size_t)bn * 64 + lane] = sacc;
        ssum += sacc; ssq = fmaf(sacc, sacc, ssq);
    }
    __syncthreads();
    red[wid][lane] = ssum; red[wid][64 + lane] = ssq;
    __syncthreads();
    const int t = threadIdx.x;
    if (t < 128) {
        float v = red[0][t] + red[1][t] + red[2][t] + red[3][t];
        part2[(size_t)blockIdx.x * 128 + t] = v;
    }
}

__global__ void k_fin2(const float* __restrict__ part2, const float* __restrict__ g,
                       const float* __restrict__ b, float* __restrict__ A,
                       float* __restrict__ Bo, int nblocks)
{
    int c = threadIdx.x;  // 64
    float S = 0.f, Q = 0.f;
    for (int k = 0; k < nblocks; ++k) { S += part2[k * 128 + c]; Q += part2[k * 128 + 64 + c]; }
    float mean = S * (1.f / 16384.f);
    float var = Q * (1.f / 16384.f) - mean * mean;
    float a = g[c] * rsqrtf(var + EPS_);
    A[c] = a; Bo[c] = b[c] - mean * a;
}

__global__ void k_update(float* __restrict__ emb, const float* __restrict__ s_buf,
                         const float* __restrict__ mask, const float* __restrict__ A2,
                         const float* __restrict__ B2)
{
    int t = blockIdx.x * 256 + threadIdx.x;
    int c = t & 63;
    int bn = t >> 6;
    float v = emb[t] * mask[bn] + fmaf(s_buf[t], A2[c], B2[c]);
    emb[t] = fmaxf(v, 0.f);
}

// ---------------- pooling / heads ----------------
__launch_bounds__(256)
__global__ void k_pool(const float* __restrict__ emb, const float* __restrict__ mask,
                       const int* __restrict__ aidx, float* __restrict__ amino,
                       float* __restrict__ psum, float* __restrict__ msum,
                       int* __restrict__ minidx)
{
    __shared__ float red[256];
    __shared__ float mred[4];
    __shared__ int kred[4];
    int t = threadIdx.x, sub = t >> 6, c = t & 63;
    int base = blockIdx.x * 32;
    int b = base >> 11;
    float pacc = 0.f, macc = 0.f;
    int kmin = 0x7fffffff;
    for (int j = 0; j < 8; ++j) {
        int bn = base + sub + 4 * j;
        float v = emb[(size_t)bn * 64 + c] * mask[bn];
        int k = aidx[bn];
        atomicAdd(&amino[(size_t)k * 64 + c], v);
        pacc += v;
        if (c == 0) { macc += mask[bn]; kmin = min(kmin, k); }
    }
    red[t] = pacc;
    if (c == 0) { mred[sub] = macc; kred[sub] = kmin; }
    __syncthreads();
    if (t < 64) {
        float tot = red[t] + red[64 + t] + red[128 + t] + red[192 + t];
        atomicAdd(&psum[b * 64 + t], tot);
    }
    if (t == 0) {
        atomicAdd(&msum[b], mred[0] + mred[1] + mred[2] + mred[3]);
        atomicMin(minidx, min(min(kred[0], kred[1]), min(kred[2], kred[3])));
    }
}

__global__ void k_amino_out(const float* __restrict__ amino, const float* __restrict__ W_af,
                            const float* __restrict__ b_af, const float* __restrict__ W_ao,
                            const float* __restrict__ b_ao, float* __restrict__ out)
{
    int t = threadIdx.x, kk = t >> 5, j = t & 31;
    int k = blockIdx.x * 8 + kk;
    float acc = b_af[j];
    for (int c = 0; c < 64; ++c)
        acc = fmaf(fmaxf(amino[(size_t)k * 64 + c], 0.f), W_af[c * 32 + j], acc);
    float h = fmaxf(acc, 0.f);
    float val = h * W_ao[j];
    for (int off = 16; off > 0; off >>= 1) val += __shfl_down(val, off, 32);
    if (j == 0) out[8 + k] = val + b_ao[0];
}

__global__ void k_protein(const float* __restrict__ psum, const float* __restrict__ msum,
                          const float* __restrict__ W_cf, const float* __restrict__ b_cf,
                          const float* __restrict__ W_out, const float* __restrict__ b_out,
                          float* __restrict__ out)
{
    int t = threadIdx.x, bb = t >> 5, j = t & 31;
    float inv = 1.f / msum[bb];
    float acc = b_cf[j];
    for (int c = 0; c < 64; ++c)
        acc = fmaf(fmaxf(psum[bb * 64 + c] * inv, 0.f), W_cf[c * 32 + j], acc);
    float h = fmaxf(acc, 0.f);
    float val = h * W_out[j];
    for (int off = 16; off > 0; off >>= 1) val += __shfl_down(val, off, 32);
    if (j == 0) out[bb] = val + b_out[0];
}

__global__ void k_maskpooled(const int* __restrict__ minidx, float* __restrict__ out)
{
    int k = blockIdx.x * 256 + threadIdx.x;
    out[8 + NAMINO_ + k] = (k < *minidx) ? 0.f : 1.f;
}

// ---------------- launch ----------------
extern "C" void kernel_launch(void* const* d_in, const int* in_sizes, int n_in,
                              void* d_out, int out_size, void* d_ws, size_t ws_size,
                              hipStream_t stream)
{
    const int* atom_idx = (const int*)d_in[0];
    const float* nbr_emb = (const float*)d_in[1];
    const int* adj = (const int*)d_in[2];
    const int* aidx = (const int*)d_in[3];
    const float* mask = (const float*)d_in[4];
    const float* et = (const float*)d_in[5];
    const float* W_emb = (const float*)d_in[6];
    const float* b_emb = (const float*)d_in[7];
    const float* fcW = (const float*)d_in[8];
    const float* fcb = (const float*)d_in[9];
    const float* bnh_g = (const float*)d_in[10];
    const float* bnh_b = (const float*)d_in[11];
    const float* bno_g = (const float*)d_in[12];
    const float* bno_b = (const float*)d_in[13];
    const float* W_cf = (const float*)d_in[14];
    const float* b_cf = (const float*)d_in[15];
    const float* W_out = (const float*)d_in[16];
    const float* b_out = (const float*)d_in[17];
    const float* W_af = (const float*)d_in[18];
    const float* b_af = (const float*)d_in[19];
    const float* W_ao = (const float*)d_in[20];
    const float* b_ao = (const float*)d_in[21];

    float* ws = (float*)d_ws;
    float* emb = ws + OFF_EMB;
    float* selfp = ws + OFF_SELF;
    float* nbrp = ws + OFF_NBR;
    float* s_buf = ws + OFF_S;
    float* T = ws + OFF_T;
    float* part1 = ws + OFF_PART1;
    float* part2 = ws + OFF_PART2;
    float* aff1A = ws + OFF_AFF1A;
    float* aff1B = ws + OFF_AFF1B;
    float* aff2A = ws + OFF_AFF2A;
    float* aff2B = ws + OFF_AFF2B;
    float* amino = ws + OFF_AMINO;
    float* psum = ws + OFF_PSUM;
    float* msum = ws + OFF_MSUM;
    int* minidx = (int*)(ws + OFF_MINIDX);
    float* out = (float*)d_out;

    // zero accumulators (amino + psum + msum contiguous), init minidx to MAX
    hipMemsetAsync(amino, 0, (131072 + 512 + 8) * sizeof(float), stream);
    hipMemsetAsync(minidx, 0x7f, sizeof(int), stream);

    k_table<<<NVOCAB, 64, 0, stream>>>(et, W_emb, b_emb, T);
    k_embed<<<NATOM * 64 / 256, 256, 0, stream>>>(atom_idx, T, emb);

    for (int i = 0; i < 4; ++i) {
        const float* Wi = fcW + (size_t)i * 160 * 128;
        k_proj<<<NATOM / 8, 256, 0, stream>>>(emb, mask, Wi, fcb + i * 128, selfp, nbrp);
        k_conv_stats<<<512, 256, 0, stream>>>(selfp, nbrp, nbr_emb, adj, mask, Wi, part1);
        k_fin1<<<1, 128, 0, stream>>>(part1, bnh_g + i * 128, bnh_b + i * 128, aff1A, aff1B, 512);
        k_conv_gate<<<512, 256, 0, stream>>>(selfp, nbrp, nbr_emb, adj, mask, Wi, aff1A, aff1B,
                                             s_buf, part2);
        k_fin2<<<1, 64, 0, stream>>>(part2, bno_g + i * 64, bno_b + i * 64, aff2A, aff2B, 512);
        k_update<<<NATOM * 64 / 256, 256, 0, stream>>>(emb, s_buf, mask, aff2A, aff2B);
    }

    k_pool<<<NATOM / 32, 256, 0, stream>>>(emb, mask, aidx, amino, psum, msum, minidx);
    k_amino_out<<<NAMINO_ / 8, 256, 0, stream>>>(amino, W_af, b_af, W_ao, b_ao, out);
    k_protein<<<1, 256, 0, stream>>>(psum, msum, W_cf, b_cf, W_out, b_out, out);
    k_maskpooled<<<NAMINO_ / 256, 256, 0, stream>>>(minidx, out);
}

// Round 2
// 598.747 us; speedup vs baseline: 3.0819x; 3.0819x over previous
//
#include <hip/hip_runtime.h>
#include <cstdint>
#include <cstddef>

#define EPS_ 1e-5f
// sizes
#define NATOM 16384      // B*N
#define NB    8
#define NN    2048
#define NM    16
#define NHA   64
#define NHB   32
#define NHG   32
#define NVOCAB 100
#define NHINIT 92
#define NAMINO_ 2048
#define NPART 1024       // partial-reduction blocks for conv kernels

// ws layout (float offsets)
#define OFF_EMB      0                 // 16384*64   = 1048576
#define OFF_SELF     1048576           // 16384*128  = 2097152
#define OFF_NBR      3145728           // 16384*128  = 2097152
#define OFF_S        5242880           // 16384*64   = 1048576
#define OFF_T        6291456           // 100*64     = 6400
#define OFF_PART1    6297856           // 1024*256   = 262144
#define OFF_PART2    6560000           // 1024*128   = 131072
#define OFF_AFF1A    6691072           // 128
#define OFF_AFF1B    6691200           // 128
#define OFF_AFF2A    6691328           // 64
#define OFF_AFF2B    6691392           // 64
#define OFF_AMINO    6691456           // 2048*64    = 131072
#define OFF_PSUM     6822528           // 8*64
#define OFF_MSUM     6823040           // 8
#define OFF_MINIDX   6823048           // 1 (int)
#define WS_FLOATS    6823049

// ---------------- embed ----------------
__global__ void k_table(const float* __restrict__ et, const float* __restrict__ W,
                        const float* __restrict__ b, float* __restrict__ T)
{
    int v = blockIdx.x, c = threadIdx.x;
    float acc = b[c];
    for (int h = 0; h < NHINIT; ++h)
        acc = fmaf(et[v * NHINIT + h], W[h * NHA + c], acc);
    T[v * NHA + c] = acc;
}

__global__ void k_embed(const int* __restrict__ idx, const float* __restrict__ T,
                        float* __restrict__ emb)
{
    int t = blockIdx.x * 256 + threadIdx.x;
    emb[t] = T[idx[t >> 6] * NHA + (t & 63)];
}

// ---------------- per-atom projections ----------------
__launch_bounds__(256)
__global__ void k_proj(const float* __restrict__ emb, const float* __restrict__ mask,
                       const float* __restrict__ fcW, const float* __restrict__ fcb,
                       float* __restrict__ selfp, float* __restrict__ nbrp)
{
    __shared__ float le[512];
    int t = threadIdx.x;
    {
        int j0 = t, j1 = t + 256;
        le[j0] = emb[blockIdx.x * 512 + j0] * mask[blockIdx.x * 8 + (j0 >> 6)];
        le[j1] = emb[blockIdx.x * 512 + j1] * mask[blockIdx.x * 8 + (j1 >> 6)];
    }
    __syncthreads();
    int half = t >> 7;        // 0 = self (with bias), 1 = nbr
    int oc = t & 127;
    float acc[8];
    float bias = half ? 0.f : fcb[oc];
#pragma unroll
    for (int a = 0; a < 8; ++a) acc[a] = bias;
    const float* Wbase = fcW + (half * 64) * 128 + oc;
    for (int c = 0; c < 64; ++c) {
        float w = Wbase[c * 128];
#pragma unroll
        for (int a = 0; a < 8; ++a) acc[a] = fmaf(le[a * 64 + c], w, acc[a]);
    }
    float* dst = half ? nbrp : selfp;
#pragma unroll
    for (int a = 0; a < 8; ++a) dst[(size_t)(blockIdx.x * 8 + a) * 128 + oc] = acc[a];
}

// ---------------- conv pass 1: z stats ----------------
// one wave per group of 4 atoms; lane owns channels (lane, lane+64)
__launch_bounds__(256, 2)
__global__ void k_conv_stats(const float* __restrict__ selfp, const float* __restrict__ nbrp,
                             const float* __restrict__ nbr_emb, const int* __restrict__ adj,
                             const float* __restrict__ mask, const float* __restrict__ fcW,
                             float* __restrict__ part1)
{
    __shared__ float se[4][512];
    __shared__ float red[4][256];
    const int lane = threadIdx.x & 63;
    const int wid = threadIdx.x >> 6;
    float we0[32], we1[32];
#pragma unroll
    for (int h = 0; h < 32; ++h) {
        we0[h] = fcW[(128 + h) * 128 + lane];
        we1[h] = fcW[(128 + h) * 128 + 64 + lane];
    }
    float sum0 = 0.f, sq0 = 0.f, sum1 = 0.f, sq1 = 0.f;
    const int base = (blockIdx.x * 4 + wid) * 4;
    for (int aa = 0; aa < 4; ++aa) {
        const int bn = base + aa;
        const int b = bn >> 11;
        const float mn = mask[bn];
        const float* src = nbr_emb + (size_t)bn * 512;
        __syncthreads();
#pragma unroll
        for (int k = 0; k < 8; ++k) se[wid][k * 64 + lane] = src[k * 64 + lane];
        int adjv = 0;
        if (lane < 16) adjv = adj[bn * 16 + lane];
        const float sp0 = selfp[(size_t)bn * 128 + lane];
        const float sp1 = selfp[(size_t)bn * 128 + 64 + lane];
        __syncthreads();
#pragma unroll 4
        for (int m = 0; m < 16; ++m) {
            const int a = __shfl(adjv, m);
            const float* np_ = nbrp + ((size_t)(b * NN + a)) * 128;
            float z0 = fmaf(mn, np_[lane], sp0);
            float z1 = fmaf(mn, np_[64 + lane], sp1);
#pragma unroll
            for (int h4 = 0; h4 < 8; ++h4) {
                const float4 e = *reinterpret_cast<const float4*>(&se[wid][m * 32 + h4 * 4]);
                z0 = fmaf(e.x, we0[h4 * 4 + 0], z0); z1 = fmaf(e.x, we1[h4 * 4 + 0], z1);
                z0 = fmaf(e.y, we0[h4 * 4 + 1], z0); z1 = fmaf(e.y, we1[h4 * 4 + 1], z1);
                z0 = fmaf(e.z, we0[h4 * 4 + 2], z0); z1 = fmaf(e.z, we1[h4 * 4 + 2], z1);
                z0 = fmaf(e.w, we0[h4 * 4 + 3], z0); z1 = fmaf(e.w, we1[h4 * 4 + 3], z1);
            }
            sum0 += z0; sq0 = fmaf(z0, z0, sq0);
            sum1 += z1; sq1 = fmaf(z1, z1, sq1);
        }
    }
    __syncthreads();
    red[wid][lane] = sum0; red[wid][64 + lane] = sum1;
    red[wid][128 + lane] = sq0; red[wid][192 + lane] = sq1;
    __syncthreads();
    const int t = threadIdx.x;
    float v = red[0][t] + red[1][t] + red[2][t] + red[3][t];
    part1[(size_t)blockIdx.x * 256 + t] = v;
}

// parallel finalize: one block per channel c (128 blocks x 256 threads)
__global__ void k_fin1(const float* __restrict__ part1, const float* __restrict__ g,
                       const float* __restrict__ b, float* __restrict__ A,
                       float* __restrict__ Bo)
{
    const int c = blockIdx.x;
    const int t = threadIdx.x;
    float S = 0.f, Q = 0.f;
    for (int k = t; k < NPART; k += 256) {
        S += part1[(size_t)k * 256 + c];
        Q += part1[(size_t)k * 256 + 128 + c];
    }
    __shared__ float sS[4], sQ[4];
#pragma unroll
    for (int off = 32; off > 0; off >>= 1) {
        S += __shfl_down(S, off, 64);
        Q += __shfl_down(Q, off, 64);
    }
    if ((t & 63) == 0) { sS[t >> 6] = S; sQ[t >> 6] = Q; }
    __syncthreads();
    if (t == 0) {
        S = sS[0] + sS[1] + sS[2] + sS[3];
        Q = sQ[0] + sQ[1] + sQ[2] + sQ[3];
        float mean = S * (1.f / 262144.f);
        float var = Q * (1.f / 262144.f) - mean * mean;
        float a = g[c] * rsqrtf(var + EPS_);
        A[c] = a; Bo[c] = b[c] - mean * a;
    }
}

// ---------------- conv pass 2: gate + s stats ----------------
__launch_bounds__(256, 2)
__global__ void k_conv_gate(const float* __restrict__ selfp, const float* __restrict__ nbrp,
                            const float* __restrict__ nbr_emb, const int* __restrict__ adj,
                            const float* __restrict__ mask, const float* __restrict__ fcW,
                            const float* __restrict__ aff1A, const float* __restrict__ aff1B,
                            float* __restrict__ s_out, float* __restrict__ part2)
{
    __shared__ float se[4][512];
    __shared__ float red[4][128];
    const int lane = threadIdx.x & 63;
    const int wid = threadIdx.x >> 6;
    float we0[32], we1[32];
#pragma unroll
    for (int h = 0; h < 32; ++h) {
        we0[h] = fcW[(128 + h) * 128 + lane];
        we1[h] = fcW[(128 + h) * 128 + 64 + lane];
    }
    const float a0 = aff1A[lane], b0 = aff1B[lane];
    const float a1 = aff1A[64 + lane], b1 = aff1B[64 + lane];
    float ssum = 0.f, ssq = 0.f;
    const int base = (blockIdx.x * 4 + wid) * 4;
    for (int aa = 0; aa < 4; ++aa) {
        const int bn = base + aa;
        const int b = bn >> 11;
        const float mn = mask[bn];
        const float* src = nbr_emb + (size_t)bn * 512;
        __syncthreads();
#pragma unroll
        for (int k = 0; k < 8; ++k) se[wid][k * 64 + lane] = src[k * 64 + lane];
        int adjv = 0;
        if (lane < 16) adjv = adj[bn * 16 + lane];
        const float sp0 = selfp[(size_t)bn * 128 + lane];
        const float sp1 = selfp[(size_t)bn * 128 + 64 + lane];
        __syncthreads();
        float sacc = 0.f;
#pragma unroll 4
        for (int m = 0; m < 16; ++m) {
            const int a = __shfl(adjv, m);
            const float* np_ = nbrp + ((size_t)(b * NN + a)) * 128;
            float z0 = fmaf(mn, np_[lane], sp0);
            float z1 = fmaf(mn, np_[64 + lane], sp1);
#pragma unroll
            for (int h4 = 0; h4 < 8; ++h4) {
                const float4 e = *reinterpret_cast<const float4*>(&se[wid][m * 32 + h4 * 4]);
                z0 = fmaf(e.x, we0[h4 * 4 + 0], z0); z1 = fmaf(e.x, we1[h4 * 4 + 0], z1);
                z0 = fmaf(e.y, we0[h4 * 4 + 1], z0); z1 = fmaf(e.y, we1[h4 * 4 + 1], z1);
                z0 = fmaf(e.z, we0[h4 * 4 + 2], z0); z1 = fmaf(e.z, we1[h4 * 4 + 2], z1);
                z0 = fmaf(e.w, we0[h4 * 4 + 3], z0); z1 = fmaf(e.w, we1[h4 * 4 + 3], z1);
            }
            float zh0 = fmaf(z0, a0, b0);          // filt channel lane
            float zh1 = fmaf(z1, a1, b1);          // core channel lane+64
            float f = 1.f / (1.f + __expf(-zh0));
            float r = fmaxf(zh1, 0.f);
            sacc = fmaf(f, r, sacc);
        }
        s_out[(size_t)bn * 64 + lane] = sacc;
        ssum += sacc; ssq = fmaf(sacc, sacc, ssq);
    }
    __syncthreads();
    red[wid][lane] = ssum; red[wid][64 + lane] = ssq;
    __syncthreads();
    const int t = threadIdx.x;
    if (t < 128) {
        float v = red[0][t] + red[1][t] + red[2][t] + red[3][t];
        part2[(size_t)blockIdx.x * 128 + t] = v;
    }
}

// parallel finalize: one block per channel c (64 blocks x 256 threads)
__global__ void k_fin2(const float* __restrict__ part2, const float* __restrict__ g,
                       const float* __restrict__ b, float* __restrict__ A,
                       float* __restrict__ Bo)
{
    const int c = blockIdx.x;
    const int t = threadIdx.x;
    float S = 0.f, Q = 0.f;
    for (int k = t; k < NPART; k += 256) {
        S += part2[(size_t)k * 128 + c];
        Q += part2[(size_t)k * 128 + 64 + c];
    }
    __shared__ float sS[4], sQ[4];
#pragma unroll
    for (int off = 32; off > 0; off >>= 1) {
        S += __shfl_down(S, off, 64);
        Q += __shfl_down(Q, off, 64);
    }
    if ((t & 63) == 0) { sS[t >> 6] = S; sQ[t >> 6] = Q; }
    __syncthreads();
    if (t == 0) {
        S = sS[0] + sS[1] + sS[2] + sS[3];
        Q = sQ[0] + sQ[1] + sQ[2] + sQ[3];
        float mean = S * (1.f / 16384.f);
        float var = Q * (1.f / 16384.f) - mean * mean;
        float a = g[c] * rsqrtf(var + EPS_);
        A[c] = a; Bo[c] = b[c] - mean * a;
    }
}

__global__ void k_update(float* __restrict__ emb, const float* __restrict__ s_buf,
                         const float* __restrict__ mask, const float* __restrict__ A2,
                         const float* __restrict__ B2)
{
    int t = blockIdx.x * 256 + threadIdx.x;
    int c = t & 63;
    int bn = t >> 6;
    float v = emb[t] * mask[bn] + fmaf(s_buf[t], A2[c], B2[c]);
    emb[t] = fmaxf(v, 0.f);
}

// ---------------- pooling / heads ----------------
__launch_bounds__(256)
__global__ void k_pool(const float* __restrict__ emb, const float* __restrict__ mask,
                       const int* __restrict__ aidx, float* __restrict__ amino,
                       float* __restrict__ psum, float* __restrict__ msum,
                       int* __restrict__ minidx)
{
    __shared__ float red[256];
    __shared__ float mred[4];
    __shared__ int kred[4];
    int t = threadIdx.x, sub = t >> 6, c = t & 63;
    int base = blockIdx.x * 32;
    int b = base >> 11;
    float pacc = 0.f, macc = 0.f;
    int kmin = 0x7fffffff;
    for (int j = 0; j < 8; ++j) {
        int bn = base + sub + 4 * j;
        float v = emb[(size_t)bn * 64 + c] * mask[bn];
        int k = aidx[bn];
        atomicAdd(&amino[(size_t)k * 64 + c], v);
        pacc += v;
        if (c == 0) { macc += mask[bn]; kmin = min(kmin, k); }
    }
    red[t] = pacc;
    if (c == 0) { mred[sub] = macc; kred[sub] = kmin; }
    __syncthreads();
    if (t < 64) {
        float tot = red[t] + red[64 + t] + red[128 + t] + red[192 + t];
        atomicAdd(&psum[b * 64 + t], tot);
    }
    if (t == 0) {
        atomicAdd(&msum[b], mred[0] + mred[1] + mred[2] + mred[3]);
        atomicMin(minidx, min(min(kred[0], kred[1]), min(kred[2], kred[3])));
    }
}

__global__ void k_amino_out(const float* __restrict__ amino, const float* __restrict__ W_af,
                            const float* __restrict__ b_af, const float* __restrict__ W_ao,
                            const float* __restrict__ b_ao, float* __restrict__ out)
{
    int t = threadIdx.x, kk = t >> 5, j = t & 31;
    int k = blockIdx.x * 8 + kk;
    float acc = b_af[j];
    for (int c = 0; c < 64; ++c)
        acc = fmaf(fmaxf(amino[(size_t)k * 64 + c], 0.f), W_af[c * 32 + j], acc);
    float h = fmaxf(acc, 0.f);
    float val = h * W_ao[j];
    for (int off = 16; off > 0; off >>= 1) val += __shfl_down(val, off, 32);
    if (j == 0) out[8 + k] = val + b_ao[0];
}

__global__ void k_protein(const float* __restrict__ psum, const float* __restrict__ msum,
                          const float* __restrict__ W_cf, const float* __restrict__ b_cf,
                          const float* __restrict__ W_out, const float* __restrict__ b_out,
                          float* __restrict__ out)
{
    int t = threadIdx.x, bb = t >> 5, j = t & 31;
    float inv = 1.f / msum[bb];
    float acc = b_cf[j];
    for (int c = 0; c < 64; ++c)
        acc = fmaf(fmaxf(psum[bb * 64 + c] * inv, 0.f), W_cf[c * 32 + j], acc);
    float h = fmaxf(acc, 0.f);
    float val = h * W_out[j];
    for (int off = 16; off > 0; off >>= 1) val += __shfl_down(val, off, 32);
    if (j == 0) out[bb] = val + b_out[0];
}

__global__ void k_maskpooled(const int* __restrict__ minidx, float* __restrict__ out)
{
    int k = blockIdx.x * 256 + threadIdx.x;
    out[8 + NAMINO_ + k] = (k < *minidx) ? 0.f : 1.f;
}

// ---------------- launch ----------------
extern "C" void kernel_launch(void* const* d_in, const int* in_sizes, int n_in,
                              void* d_out, int out_size, void* d_ws, size_t ws_size,
                              hipStream_t stream)
{
    const int* atom_idx = (const int*)d_in[0];
    const float* nbr_emb = (const float*)d_in[1];
    const int* adj = (const int*)d_in[2];
    const int* aidx = (const int*)d_in[3];
    const float* mask = (const float*)d_in[4];
    const float* et = (const float*)d_in[5];
    const float* W_emb = (const float*)d_in[6];
    const float* b_emb = (const float*)d_in[7];
    const float* fcW = (const float*)d_in[8];
    const float* fcb = (const float*)d_in[9];
    const float* bnh_g = (const float*)d_in[10];
    const float* bnh_b = (const float*)d_in[11];
    const float* bno_g = (const float*)d_in[12];
    const float* bno_b = (const float*)d_in[13];
    const float* W_cf = (const float*)d_in[14];
    const float* b_cf = (const float*)d_in[15];
    const float* W_out = (const float*)d_in[16];
    const float* b_out = (const float*)d_in[17];
    const float* W_af = (const float*)d_in[18];
    const float* b_af = (const float*)d_in[19];
    const float* W_ao = (const float*)d_in[20];
    const float* b_ao = (const float*)d_in[21];

    float* ws = (float*)d_ws;
    float* emb = ws + OFF_EMB;
    float* selfp = ws + OFF_SELF;
    float* nbrp = ws + OFF_NBR;
    float* s_buf = ws + OFF_S;
    float* T = ws + OFF_T;
    float* part1 = ws + OFF_PART1;
    float* part2 = ws + OFF_PART2;
    float* aff1A = ws + OFF_AFF1A;
    float* aff1B = ws + OFF_AFF1B;
    float* aff2A = ws + OFF_AFF2A;
    float* aff2B = ws + OFF_AFF2B;
    float* amino = ws + OFF_AMINO;
    float* psum = ws + OFF_PSUM;
    float* msum = ws + OFF_MSUM;
    int* minidx = (int*)(ws + OFF_MINIDX);
    float* out = (float*)d_out;

    // zero accumulators (amino + psum + msum contiguous), init minidx to MAX
    hipMemsetAsync(amino, 0, (131072 + 512 + 8) * sizeof(float), stream);
    hipMemsetAsync(minidx, 0x7f, sizeof(int), stream);

    k_table<<<NVOCAB, 64, 0, stream>>>(et, W_emb, b_emb, T);
    k_embed<<<NATOM * 64 / 256, 256, 0, stream>>>(atom_idx, T, emb);

    for (int i = 0; i < 4; ++i) {
        const float* Wi = fcW + (size_t)i * 160 * 128;
        k_proj<<<NATOM / 8, 256, 0, stream>>>(emb, mask, Wi, fcb + i * 128, selfp, nbrp);
        k_conv_stats<<<NPART, 256, 0, stream>>>(selfp, nbrp, nbr_emb, adj, mask, Wi, part1);
        k_fin1<<<128, 256, 0, stream>>>(part1, bnh_g + i * 128, bnh_b + i * 128, aff1A, aff1B);
        k_conv_gate<<<NPART, 256, 0, stream>>>(selfp, nbrp, nbr_emb, adj, mask, Wi, aff1A, aff1B,
                                               s_buf, part2);
        k_fin2<<<64, 256, 0, stream>>>(part2, bno_g + i * 64, bno_b + i * 64, aff2A, aff2B);
        k_update<<<NATOM * 64 / 256, 256, 0, stream>>>(emb, s_buf, mask, aff2A, aff2B);
    }

    k_pool<<<NATOM / 32, 256, 0, stream>>>(emb, mask, aidx, amino, psum, msum, minidx);
    k_amino_out<<<NAMINO_ / 8, 256, 0, stream>>>(amino, W_af, b_af, W_ao, b_ao, out);
    k_protein<<<1, 256, 0, stream>>>(psum, msum, W_cf, b_cf, W_out, b_out, out);
    k_maskpooled<<<NAMINO_ / 256, 256, 0, stream>>>(minidx, out);
}

// Round 3
// 355.641 us; speedup vs baseline: 5.1886x; 1.6836x over previous
//
#include <hip/hip_runtime.h>
#include <cstdint>
#include <cstddef>

#define EPS_ 1e-5f
// sizes
#define NATOM 16384      // B*N
#define NB    8
#define NN    2048
#define NM    16
#define NHA   64
#define NHB   32
#define NHG   32
#define NVOCAB 100
#define NHINIT 92
#define NAMINO_ 2048
#define NPART 1024       // partial-reduction blocks for conv kernels

// ws layout (float offsets)
#define OFF_EMB      0                 // 16384*64   = 1048576
#define OFF_SELF     1048576           // 16384*128  = 2097152
#define OFF_NBR      3145728           // 16384*128  = 2097152
#define OFF_S        5242880           // 16384*64   = 1048576
#define OFF_T        6291456           // 100*64     = 6400
#define OFF_PART1    6297856           // 1024*256   = 262144
#define OFF_PART2    6560000           // 1024*128   = 131072
#define OFF_AFF1A    6691072           // 128
#define OFF_AFF1B    6691200           // 128
#define OFF_AFF2A    6691328           // 64
#define OFF_AFF2B    6691392           // 64
#define OFF_AMINO    6691456           // 2048*64    = 131072
#define OFF_PSUM     6822528           // 8*64
#define OFF_MSUM     6823040           // 8
#define OFF_MINIDX   6823048           // 1 (int)
#define OFF_PACK     6823168           // 16384*64*4 floats-worth = 16.78 MB (bf16 A-frags)
#define WS_FLOATS    (6823168 + 4194304)

typedef __attribute__((ext_vector_type(8))) short bf16x8;
typedef __attribute__((ext_vector_type(4))) float f32x4;

static __device__ __forceinline__ short f2bf(float f) {
    union { float f; uint32_t u; } v; v.f = f;
    uint32_t r = v.u + 0x7fffu + ((v.u >> 16) & 1u);   // RNE
    return (short)(r >> 16);
}

// ---------------- embed ----------------
__global__ void k_table(const float* __restrict__ et, const float* __restrict__ W,
                        const float* __restrict__ b, float* __restrict__ T)
{
    int v = blockIdx.x, c = threadIdx.x;
    float acc = b[c];
    for (int h = 0; h < NHINIT; ++h)
        acc = fmaf(et[v * NHINIT + h], W[h * NHA + c], acc);
    T[v * NHA + c] = acc;
}

__global__ void k_embed(const int* __restrict__ idx, const float* __restrict__ T,
                        float* __restrict__ emb)
{
    int t = blockIdx.x * 256 + threadIdx.x;
    emb[t] = T[idx[t >> 6] * NHA + (t & 63)];
}

// ---------------- pack nbr_emb into bf16 MFMA A-fragment layout ----------------
// pack[bn][lane][j] = bf16(nbr_emb[bn][m = lane&15][k = (lane>>4)*8 + j])
__global__ void k_pack(const float* __restrict__ nbr_emb, uint4* __restrict__ pack)
{
    int t = blockIdx.x * 256 + threadIdx.x;     // over 16384*64
    int bn = t >> 6, l = t & 63;
    const float* src = nbr_emb + (size_t)bn * 512 + (l & 15) * 32 + (l >> 4) * 8;
    float4 a = *reinterpret_cast<const float4*>(src);
    float4 b = *reinterpret_cast<const float4*>(src + 4);
    union { short s[8]; uint4 u; } o;
    o.s[0] = f2bf(a.x); o.s[1] = f2bf(a.y); o.s[2] = f2bf(a.z); o.s[3] = f2bf(a.w);
    o.s[4] = f2bf(b.x); o.s[5] = f2bf(b.y); o.s[6] = f2bf(b.z); o.s[7] = f2bf(b.w);
    pack[t] = o.u;
}

// ---------------- per-atom projections ----------------
__launch_bounds__(256)
__global__ void k_proj(const float* __restrict__ emb, const float* __restrict__ mask,
                       const float* __restrict__ fcW, const float* __restrict__ fcb,
                       float* __restrict__ selfp, float* __restrict__ nbrp)
{
    __shared__ float le[512];
    int t = threadIdx.x;
    {
        int j0 = t, j1 = t + 256;
        le[j0] = emb[blockIdx.x * 512 + j0] * mask[blockIdx.x * 8 + (j0 >> 6)];
        le[j1] = emb[blockIdx.x * 512 + j1] * mask[blockIdx.x * 8 + (j1 >> 6)];
    }
    __syncthreads();
    int half = t >> 7;        // 0 = self (with bias), 1 = nbr
    int oc = t & 127;
    float acc[8];
    float bias = half ? 0.f : fcb[oc];
#pragma unroll
    for (int a = 0; a < 8; ++a) acc[a] = bias;
    const float* Wbase = fcW + (half * 64) * 128 + oc;
    for (int c = 0; c < 64; ++c) {
        float w = Wbase[c * 128];
#pragma unroll
        for (int a = 0; a < 8; ++a) acc[a] = fmaf(le[a * 64 + c], w, acc[a]);
    }
    float* dst = half ? nbrp : selfp;
#pragma unroll
    for (int a = 0; a < 8; ++a) dst[(size_t)(blockIdx.x * 8 + a) * 128 + oc] = acc[a];
}

// ---------------- conv pass 1: z stats (MFMA e-term) ----------------
// 4 waves/block, 4 atoms per wave. Lane owns D cols ch=cb*16+(lane&15), rows m=(lane>>4)*4+r.
__launch_bounds__(256, 4)
__global__ void k_conv_stats(const float* __restrict__ selfp, const float* __restrict__ nbrp,
                             const uint4* __restrict__ pack, const int* __restrict__ adj,
                             const float* __restrict__ mask, const float* __restrict__ fcW,
                             float* __restrict__ part1)
{
    __shared__ float red[4][256];
    const int lane = threadIdx.x & 63;
    const int wid = threadIdx.x >> 6;
    const int l15 = lane & 15, lg = lane >> 4;
    // B-frags for W_e (rows 128..159 of fcW): lane holds W[k=lg*8+j][cb*16+l15]
    const float* We = fcW + 128 * 128;
    bf16x8 Wb[8];
#pragma unroll
    for (int cb = 0; cb < 8; ++cb) {
        union { short s[8]; bf16x8 v; } w;
#pragma unroll
        for (int j = 0; j < 8; ++j)
            w.s[j] = f2bf(We[(lg * 8 + j) * 128 + cb * 16 + l15]);
        Wb[cb] = w.v;
    }
    float sum[8] = {0, 0, 0, 0, 0, 0, 0, 0};
    float sq[8] = {0, 0, 0, 0, 0, 0, 0, 0};
    const int base = (blockIdx.x * 4 + wid) * 4;
    for (int aa = 0; aa < 4; ++aa) {
        const int bn = base + aa;
        const int b = bn >> 11;
        const float mn = mask[bn];
        int adjv = 0;
        if (lane < 16) adjv = adj[bn * 16 + lane];
        union { uint4 u; bf16x8 v; } af;
        af.u = pack[(size_t)bn * 64 + lane];
        float sp[8];
#pragma unroll
        for (int cb = 0; cb < 8; ++cb) sp[cb] = selfp[(size_t)bn * 128 + cb * 16 + l15];
        const float* npb = nbrp + (size_t)b * NN * 128;
        f32x4 acc[8];
#pragma unroll
        for (int r = 0; r < 4; ++r) {
            const int am = __shfl(adjv, lg * 4 + r);
            const float* rowp = npb + (size_t)am * 128;
#pragma unroll
            for (int cb = 0; cb < 8; ++cb)
                acc[cb][r] = fmaf(mn, rowp[cb * 16 + l15], sp[cb]);
        }
#pragma unroll
        for (int cb = 0; cb < 8; ++cb)
            acc[cb] = __builtin_amdgcn_mfma_f32_16x16x32_bf16(af.v, Wb[cb], acc[cb], 0, 0, 0);
#pragma unroll
        for (int cb = 0; cb < 8; ++cb) {
#pragma unroll
            for (int r = 0; r < 4; ++r) {
                float z = acc[cb][r];
                sum[cb] += z; sq[cb] = fmaf(z, z, sq[cb]);
            }
        }
    }
#pragma unroll
    for (int cb = 0; cb < 8; ++cb) {
        sum[cb] += __shfl_xor(sum[cb], 16);
        sum[cb] += __shfl_xor(sum[cb], 32);
        sq[cb] += __shfl_xor(sq[cb], 16);
        sq[cb] += __shfl_xor(sq[cb], 32);
    }
    if (lane < 16) {
#pragma unroll
        for (int cb = 0; cb < 8; ++cb) {
            red[wid][cb * 16 + lane] = sum[cb];
            red[wid][128 + cb * 16 + lane] = sq[cb];
        }
    }
    __syncthreads();
    const int t = threadIdx.x;
    part1[(size_t)blockIdx.x * 256 + t] = red[0][t] + red[1][t] + red[2][t] + red[3][t];
}

// parallel finalize: one block per channel c (128 blocks x 256 threads)
__global__ void k_fin1(const float* __restrict__ part1, const float* __restrict__ g,
                       const float* __restrict__ b, float* __restrict__ A,
                       float* __restrict__ Bo)
{
    const int c = blockIdx.x;
    const int t = threadIdx.x;
    float S = 0.f, Q = 0.f;
    for (int k = t; k < NPART; k += 256) {
        S += part1[(size_t)k * 256 + c];
        Q += part1[(size_t)k * 256 + 128 + c];
    }
    __shared__ float sS[4], sQ[4];
#pragma unroll
    for (int off = 32; off > 0; off >>= 1) {
        S += __shfl_down(S, off, 64);
        Q += __shfl_down(Q, off, 64);
    }
    if ((t & 63) == 0) { sS[t >> 6] = S; sQ[t >> 6] = Q; }
    __syncthreads();
    if (t == 0) {
        S = sS[0] + sS[1] + sS[2] + sS[3];
        Q = sQ[0] + sQ[1] + sQ[2] + sQ[3];
        float mean = S * (1.f / 262144.f);
        float var = Q * (1.f / 262144.f) - mean * mean;
        float a = g[c] * rsqrtf(var + EPS_);
        A[c] = a; Bo[c] = b[c] - mean * a;
    }
}

// ---------------- conv pass 2: gate + s stats (MFMA e-term) ----------------
__launch_bounds__(256, 4)
__global__ void k_conv_gate(const float* __restrict__ selfp, const float* __restrict__ nbrp,
                            const uint4* __restrict__ pack, const int* __restrict__ adj,
                            const float* __restrict__ mask, const float* __restrict__ fcW,
                            const float* __restrict__ aff1A, const float* __restrict__ aff1B,
                            float* __restrict__ s_out, float* __restrict__ part2)
{
    __shared__ float red[4][128];
    const int lane = threadIdx.x & 63;
    const int wid = threadIdx.x >> 6;
    const int l15 = lane & 15, lg = lane >> 4;
    const float* We = fcW + 128 * 128;
    bf16x8 Wb[8];
#pragma unroll
    for (int cb = 0; cb < 8; ++cb) {
        union { short s[8]; bf16x8 v; } w;
#pragma unroll
        for (int j = 0; j < 8; ++j)
            w.s[j] = f2bf(We[(lg * 8 + j) * 128 + cb * 16 + l15]);
        Wb[cb] = w.v;
    }
    float aA[8], aB[8];
#pragma unroll
    for (int cb = 0; cb < 8; ++cb) {
        aA[cb] = aff1A[cb * 16 + l15];
        aB[cb] = aff1B[cb * 16 + l15];
    }
    float ssum[4] = {0, 0, 0, 0}, ssq[4] = {0, 0, 0, 0};
    const int base = (blockIdx.x * 4 + wid) * 4;
    for (int aa = 0; aa < 4; ++aa) {
        const int bn = base + aa;
        const int b = bn >> 11;
        const float mn = mask[bn];
        int adjv = 0;
        if (lane < 16) adjv = adj[bn * 16 + lane];
        union { uint4 u; bf16x8 v; } af;
        af.u = pack[(size_t)bn * 64 + lane];
        float sp[8];
#pragma unroll
        for (int cb = 0; cb < 8; ++cb) sp[cb] = selfp[(size_t)bn * 128 + cb * 16 + l15];
        const float* npb = nbrp + (size_t)b * NN * 128;
        f32x4 acc[8];
#pragma unroll
        for (int r = 0; r < 4; ++r) {
            const int am = __shfl(adjv, lg * 4 + r);
            const float* rowp = npb + (size_t)am * 128;
#pragma unroll
            for (int cb = 0; cb < 8; ++cb)
                acc[cb][r] = fmaf(mn, rowp[cb * 16 + l15], sp[cb]);
        }
#pragma unroll
        for (int cb = 0; cb < 8; ++cb)
            acc[cb] = __builtin_amdgcn_mfma_f32_16x16x32_bf16(af.v, Wb[cb], acc[cb], 0, 0, 0);
        // gate: filt ch = cb*16+l15 (cb<4), core ch+64 -> acc[cb+4] same lane
        float sv[4];
#pragma unroll
        for (int cb = 0; cb < 4; ++cb) {
            float s = 0.f;
#pragma unroll
            for (int r = 0; r < 4; ++r) {
                float zf = fmaf(acc[cb][r], aA[cb], aB[cb]);
                float zc = fmaf(acc[cb + 4][r], aA[cb + 4], aB[cb + 4]);
                float f = 1.f / (1.f + __expf(-zf));
                s = fmaf(f, fmaxf(zc, 0.f), s);
            }
            // reduce partial (this lane's 4 m) across lane groups -> full sum over 16 m
            s += __shfl_xor(s, 16);
            s += __shfl_xor(s, 32);
            sv[cb] = s;
            ssum[cb] += s; ssq[cb] = fmaf(s, s, ssq[cb]);
        }
        if (lane < 16) {
#pragma unroll
            for (int cb = 0; cb < 4; ++cb)
                s_out[(size_t)bn * 64 + cb * 16 + lane] = sv[cb];
        }
    }
    if (lane < 16) {
#pragma unroll
        for (int cb = 0; cb < 4; ++cb) {
            red[wid][cb * 16 + lane] = ssum[cb];
            red[wid][64 + cb * 16 + lane] = ssq[cb];
        }
    }
    __syncthreads();
    const int t = threadIdx.x;
    if (t < 128) {
        part2[(size_t)blockIdx.x * 128 + t] = red[0][t] + red[1][t] + red[2][t] + red[3][t];
    }
}

// parallel finalize: one block per channel c (64 blocks x 256 threads)
__global__ void k_fin2(const float* __restrict__ part2, const float* __restrict__ g,
                       const float* __restrict__ b, float* __restrict__ A,
                       float* __restrict__ Bo)
{
    const int c = blockIdx.x;
    const int t = threadIdx.x;
    float S = 0.f, Q = 0.f;
    for (int k = t; k < NPART; k += 256) {
        S += part2[(size_t)k * 128 + c];
        Q += part2[(size_t)k * 128 + 64 + c];
    }
    __shared__ float sS[4], sQ[4];
#pragma unroll
    for (int off = 32; off > 0; off >>= 1) {
        S += __shfl_down(S, off, 64);
        Q += __shfl_down(Q, off, 64);
    }
    if ((t & 63) == 0) { sS[t >> 6] = S; sQ[t >> 6] = Q; }
    __syncthreads();
    if (t == 0) {
        S = sS[0] + sS[1] + sS[2] + sS[3];
        Q = sQ[0] + sQ[1] + sQ[2] + sQ[3];
        float mean = S * (1.f / 16384.f);
        float var = Q * (1.f / 16384.f) - mean * mean;
        float a = g[c] * rsqrtf(var + EPS_);
        A[c] = a; Bo[c] = b[c] - mean * a;
    }
}

__global__ void k_update(float* __restrict__ emb, const float* __restrict__ s_buf,
                         const float* __restrict__ mask, const float* __restrict__ A2,
                         const float* __restrict__ B2)
{
    int t = blockIdx.x * 256 + threadIdx.x;
    int c = t & 63;
    int bn = t >> 6;
    float v = emb[t] * mask[bn] + fmaf(s_buf[t], A2[c], B2[c]);
    emb[t] = fmaxf(v, 0.f);
}

// ---------------- pooling / heads ----------------
__launch_bounds__(256)
__global__ void k_pool(const float* __restrict__ emb, const float* __restrict__ mask,
                       const int* __restrict__ aidx, float* __restrict__ amino,
                       float* __restrict__ psum, float* __restrict__ msum,
                       int* __restrict__ minidx)
{
    __shared__ float red[256];
    __shared__ float mred[4];
    __shared__ int kred[4];
    int t = threadIdx.x, sub = t >> 6, c = t & 63;
    int base = blockIdx.x * 32;
    int b = base >> 11;
    float pacc = 0.f, macc = 0.f;
    int kmin = 0x7fffffff;
    for (int j = 0; j < 8; ++j) {
        int bn = base + sub + 4 * j;
        float v = emb[(size_t)bn * 64 + c] * mask[bn];
        int k = aidx[bn];
        atomicAdd(&amino[(size_t)k * 64 + c], v);
        pacc += v;
        if (c == 0) { macc += mask[bn]; kmin = min(kmin, k); }
    }
    red[t] = pacc;
    if (c == 0) { mred[sub] = macc; kred[sub] = kmin; }
    __syncthreads();
    if (t < 64) {
        float tot = red[t] + red[64 + t] + red[128 + t] + red[192 + t];
        atomicAdd(&psum[b * 64 + t], tot);
    }
    if (t == 0) {
        atomicAdd(&msum[b], mred[0] + mred[1] + mred[2] + mred[3]);
        atomicMin(minidx, min(min(kred[0], kred[1]), min(kred[2], kred[3])));
    }
}

__global__ void k_amino_out(const float* __restrict__ amino, const float* __restrict__ W_af,
                            const float* __restrict__ b_af, const float* __restrict__ W_ao,
                            const float* __restrict__ b_ao, float* __restrict__ out)
{
    int t = threadIdx.x, kk = t >> 5, j = t & 31;
    int k = blockIdx.x * 8 + kk;
    float acc = b_af[j];
    for (int c = 0; c < 64; ++c)
        acc = fmaf(fmaxf(amino[(size_t)k * 64 + c], 0.f), W_af[c * 32 + j], acc);
    float h = fmaxf(acc, 0.f);
    float val = h * W_ao[j];
    for (int off = 16; off > 0; off >>= 1) val += __shfl_down(val, off, 32);
    if (j == 0) out[8 + k] = val + b_ao[0];
}

__global__ void k_protein(const float* __restrict__ psum, const float* __restrict__ msum,
                          const float* __restrict__ W_cf, const float* __restrict__ b_cf,
                          const float* __restrict__ W_out, const float* __restrict__ b_out,
                          float* __restrict__ out)
{
    int t = threadIdx.x, bb = t >> 5, j = t & 31;
    float inv = 1.f / msum[bb];
    float acc = b_cf[j];
    for (int c = 0; c < 64; ++c)
        acc = fmaf(fmaxf(psum[bb * 64 + c] * inv, 0.f), W_cf[c * 32 + j], acc);
    float h = fmaxf(acc, 0.f);
    float val = h * W_out[j];
    for (int off = 16; off > 0; off >>= 1) val += __shfl_down(val, off, 32);
    if (j == 0) out[bb] = val + b_out[0];
}

__global__ void k_maskpooled(const int* __restrict__ minidx, float* __restrict__ out)
{
    int k = blockIdx.x * 256 + threadIdx.x;
    out[8 + NAMINO_ + k] = (k < *minidx) ? 0.f : 1.f;
}

// ---------------- launch ----------------
extern "C" void kernel_launch(void* const* d_in, const int* in_sizes, int n_in,
                              void* d_out, int out_size, void* d_ws, size_t ws_size,
                              hipStream_t stream)
{
    const int* atom_idx = (const int*)d_in[0];
    const float* nbr_emb = (const float*)d_in[1];
    const int* adj = (const int*)d_in[2];
    const int* aidx = (const int*)d_in[3];
    const float* mask = (const float*)d_in[4];
    const float* et = (const float*)d_in[5];
    const float* W_emb = (const float*)d_in[6];
    const float* b_emb = (const float*)d_in[7];
    const float* fcW = (const float*)d_in[8];
    const float* fcb = (const float*)d_in[9];
    const float* bnh_g = (const float*)d_in[10];
    const float* bnh_b = (const float*)d_in[11];
    const float* bno_g = (const float*)d_in[12];
    const float* bno_b = (const float*)d_in[13];
    const float* W_cf = (const float*)d_in[14];
    const float* b_cf = (const float*)d_in[15];
    const float* W_out = (const float*)d_in[16];
    const float* b_out = (const float*)d_in[17];
    const float* W_af = (const float*)d_in[18];
    const float* b_af = (const float*)d_in[19];
    const float* W_ao = (const float*)d_in[20];
    const float* b_ao = (const float*)d_in[21];

    float* ws = (float*)d_ws;
    float* emb = ws + OFF_EMB;
    float* selfp = ws + OFF_SELF;
    float* nbrp = ws + OFF_NBR;
    float* s_buf = ws + OFF_S;
    float* T = ws + OFF_T;
    float* part1 = ws + OFF_PART1;
    float* part2 = ws + OFF_PART2;
    float* aff1A = ws + OFF_AFF1A;
    float* aff1B = ws + OFF_AFF1B;
    float* aff2A = ws + OFF_AFF2A;
    float* aff2B = ws + OFF_AFF2B;
    float* amino = ws + OFF_AMINO;
    float* psum = ws + OFF_PSUM;
    float* msum = ws + OFF_MSUM;
    int* minidx = (int*)(ws + OFF_MINIDX);
    uint4* pack = (uint4*)(ws + OFF_PACK);
    float* out = (float*)d_out;

    // zero accumulators (amino + psum + msum contiguous), init minidx to MAX
    hipMemsetAsync(amino, 0, (131072 + 512 + 8) * sizeof(float), stream);
    hipMemsetAsync(minidx, 0x7f, sizeof(int), stream);

    k_table<<<NVOCAB, 64, 0, stream>>>(et, W_emb, b_emb, T);
    k_embed<<<NATOM * 64 / 256, 256, 0, stream>>>(atom_idx, T, emb);
    k_pack<<<NATOM * 64 / 256, 256, 0, stream>>>(nbr_emb, pack);

    for (int i = 0; i < 4; ++i) {
        const float* Wi = fcW + (size_t)i * 160 * 128;
        k_proj<<<NATOM / 8, 256, 0, stream>>>(emb, mask, Wi, fcb + i * 128, selfp, nbrp);
        k_conv_stats<<<NPART, 256, 0, stream>>>(selfp, nbrp, pack, adj, mask, Wi, part1);
        k_fin1<<<128, 256, 0, stream>>>(part1, bnh_g + i * 128, bnh_b + i * 128, aff1A, aff1B);
        k_conv_gate<<<NPART, 256, 0, stream>>>(selfp, nbrp, pack, adj, mask, Wi, aff1A, aff1B,
                                               s_buf, part2);
        k_fin2<<<64, 256, 0, stream>>>(part2, bno_g + i * 64, bno_b + i * 64, aff2A, aff2B);
        k_update<<<NATOM * 64 / 256, 256, 0, stream>>>(emb, s_buf, mask, aff2A, aff2B);
    }

    k_pool<<<NATOM / 32, 256, 0, stream>>>(emb, mask, aidx, amino, psum, msum, minidx);
    k_amino_out<<<NAMINO_ / 8, 256, 0, stream>>>(amino, W_af, b_af, W_ao, b_ao, out);
    k_protein<<<1, 256, 0, stream>>>(psum, msum, W_cf, b_cf, W_out, b_out, out);
    k_maskpooled<<<NAMINO_ / 256, 256, 0, stream>>>(minidx, out);
}